// Round 17
// baseline (142.000 us; speedup 1.0000x reference)
//
#include <hip/hip_runtime.h>
#include <hip/hip_bf16.h>
#include <cmath>

#define HID 128
#define TM 64           // tile rows
#define TPB 4           // tiles per block (W loaded once per block)
#define MAXK 8          // max tiles a segment can span (seg len <= ~512)
#define PIECE_F 132     // floats per piece: [m, d, pad, pad, p[128]]
#define XP 132          // shorts per LDS X row: 264B pitch -> <=2-way banks

typedef __attribute__((ext_vector_type(8))) short bf16x8;
typedef __attribute__((ext_vector_type(16))) float f32x16;
typedef __attribute__((ext_vector_type(4))) float f32x4;
typedef __attribute__((ext_vector_type(2))) float f32x2;

__device__ __forceinline__ float exp2_fast(float x) {
    float r;
    asm("v_exp_f32 %0, %1" : "=v"(r) : "v"(x));
    return r;
}

// Pack 8 floats -> 8 bf16 RNE via hardware cvt (pairs into v_cvt_pk_bf16_f32).
__device__ __forceinline__ bf16x8 pack8(const float* f) {
    union { short h8[8]; bf16x8 v; } u;
    #pragma unroll
    for (int q = 0; q < 8; ++q)
        u.h8[q] = (short)__bfloat16_as_ushort(__float2bfloat16(f[q]));
    return u.v;
}

// 4x tanh with ONE v_rcp: tanh = 1 - 2/(E+1), E = exp2(arg); reciprocals of
// a_i = E_i+1 reconstructed from rcp(a0*a1*a2*a3). a_i in [1, ~1.2e6] so the
// product <= ~2e24 (no overflow). s += sum w_i * tanh_i.
__device__ __forceinline__ void tanh4(const float* arg, const float* w, float& s) {
    float a0 = exp2_fast(arg[0]) + 1.0f;
    float a1 = exp2_fast(arg[1]) + 1.0f;
    float a2 = exp2_fast(arg[2]) + 1.0f;
    float a3 = exp2_fast(arg[3]) + 1.0f;
    float p01 = a0 * a1, p23 = a2 * a3;
    float r = __builtin_amdgcn_rcpf(p01 * p23);
    float r01 = r * p23, r23 = r * p01;      // 1/p01, 1/p23
    float i0 = r01 * a1, i1 = r01 * a0;      // 1/a0, 1/a1
    float i2 = r23 * a3, i3 = r23 * a2;
    s = fmaf(w[0], fmaf(-2.0f, i0, 1.0f), s);
    s = fmaf(w[1], fmaf(-2.0f, i1, 1.0f), s);
    s = fmaf(w[2], fmaf(-2.0f, i2, 1.0f), s);
    s = fmaf(w[3], fmaf(-2.0f, i3, 1.0f), s);
}

// ---------------------------------------------------------------------------
// Prep: W -> bf16 RNE in per-wave register-fragment order for 32x32x16:
// id = (wv*8 + kc)*64 + lane holds W[wv*32 + (lane&31)][kc*16 + (lane>>5)*8 + q]
// ---------------------------------------------------------------------------
__global__ __launch_bounds__(256) void prep_w_frag(
    const float* __restrict__ W, short* __restrict__ whi)
{
    int id = blockIdx.x * 256 + threadIdx.x;    // 0..2047
    int l  = id & 63;
    int kc = (id >> 6) & 7;
    int wv = id >> 9;                           // 0..3
    int j  = wv * 32 + (l & 31);
    int k0 = kc * 16 + ((l >> 5) << 3);
    const float* src = W + j * HID + k0;
    float a8[8];
    #pragma unroll
    for (int q = 0; q < 8; ++q) a8[q] = src[q];
    *(bf16x8*)(whi + (size_t)id * 8) = pack8(a8);
}

// ---------------------------------------------------------------------------
// Segment starts from sorted owners (int32/int64) + first-segment per TM-tile.
// ---------------------------------------------------------------------------
__global__ void seg_start_kernel(const int* __restrict__ ow,
                                 int* __restrict__ seg_start,
                                 int* __restrict__ fseg, int N, int S)
{
    const int is64 = (ow[(size_t)N - 1] == 0) ? 1 : 0;
    long i = (long)blockIdx.x * blockDim.x + threadIdx.x;
    if (i > N) return;
    int a = (i == 0) ? -1 : ow[is64 ? (size_t)(2 * (i - 1)) : (size_t)(i - 1)];
    int b = (i == N) ? S  : ow[is64 ? (size_t)(2 * i)       : (size_t)i];
    for (int s = a + 1; s <= b; ++s) seg_start[s] = (int)i;
    if (i < N && (i & (TM - 1)) == 0) fseg[i >> 6] = b;  // owner of row i
}

// ---------------------------------------------------------------------------
// Fused, multi-tile: each block processes TPB consecutive 64-row tiles with
// its W slice (8 frags = 32 VGPRs) loaded ONCE -> W L2 traffic / TPB.
// Per-tile body identical to the 126us round-12 kernel.
// ---------------------------------------------------------------------------
__global__ __launch_bounds__(256, 4) void fused_kernel(
    const float* __restrict__ X, const short* __restrict__ whi_g,
    const float* __restrict__ bproj, const float* __restrict__ wscore,
    const int* __restrict__ seg_start, const int* __restrict__ fseg,
    float* __restrict__ pieces, int N, int S, int NT)
{
    __shared__ __align__(16) short X_lds[TM * XP];   // ~16.9 KB
    __shared__ float u_part[4][TM];
    __shared__ float w_lds[TM];
    __shared__ float bw_lds[2 * HID];                // packed {2.885*b[j], w[j]}

    const int tid  = threadIdx.x;
    const int lane = tid & 63;
    const int wv   = tid >> 6;
    const int l31  = lane & 31;
    const int hig  = lane >> 5;

    // --- W slice for this wave: loaded once per block ---
    bf16x8 wf[8];
    #pragma unroll
    for (int kc = 0; kc < 8; ++kc)
        wf[kc] = *(const bf16x8*)(whi_g + (size_t)((wv * 8 + kc) * 64 + lane) * 8);

    if (tid < HID) {
        bw_lds[2 * tid]     = 2.885390082f * bproj[tid];   // pre-scaled
        bw_lds[2 * tid + 1] = wscore[tid];
    }

    const int Tend0 = (blockIdx.x + 1) * TPB;
    const int Tend  = (Tend0 < NT) ? Tend0 : NT;

    for (int T = blockIdx.x * TPB; T < Tend; ++T) {
        const int rbase = T * TM;
        const int limit = (N - rbase < TM) ? (N - rbase) : TM;

        const int sseg0 = fseg[T];
        int svl = sseg0 + lane;
        int sv  = seg_start[(svl <= S) ? svl : S];

        // --- stage X: read 32B f32, cvt bf16, write 16B chunk (pitch XP) ---
        #pragma unroll
        for (int it = 0; it < 4; ++it) {
            int id = it * 256 + tid;          // 0..1023
            int r  = id >> 4;                 // 0..63
            int c  = id & 15;                 // 8-elem chunk
            int grow = rbase + r;
            if (grow >= N) grow = N - 1;
            float a8[8];
            *(f32x4*)(a8)     = *(const f32x4*)(X + (size_t)grow * HID + c * 8);
            *(f32x4*)(a8 + 4) = *(const f32x4*)(X + (size_t)grow * HID + c * 8 + 4);
            *(bf16x8*)(&X_lds[r * XP + c * 8]) = pack8(a8);
        }
        __syncthreads();

        // ---- MFMA 32x32x16: acc0 covers i=l31, acc1 covers i=32+l31 ----
        f32x16 acc0, acc1;
        #pragma unroll
        for (int g = 0; g < 16; ++g) { acc0[g] = 0.0f; acc1[g] = 0.0f; }

        #pragma unroll
        for (int kc = 0; kc < 8; ++kc) {
            int c = kc * 2 + hig;             // chunk holding this lane's k-octet
            bf16x8 x0 = *(const bf16x8*)(&X_lds[l31 * XP + c * 8]);
            bf16x8 x1 = *(const bf16x8*)(&X_lds[(32 + l31) * XP + c * 8]);
            acc0 = __builtin_amdgcn_mfma_f32_32x32x16_bf16(wf[kc], x0, acc0, 0, 0, 0);
            acc1 = __builtin_amdgcn_mfma_f32_32x32x16_bf16(wf[kc], x1, acc1, 0, 0, 0);
        }

        // ---- epilogue: partial u over this wave's 32 j's ----
        // D layout (32x32): col i = lane&31; row j = (reg&3)+8*(reg>>2)+4*hig
        float s0 = 0.0f, s1 = 0.0f;
        #pragma unroll
        for (int g4 = 0; g4 < 4; ++g4) {
            float arg0[4], arg1[4], w4[4];
            #pragma unroll
            for (int q = 0; q < 4; ++q) {
                int reg = g4 * 4 + q;
                int j = wv * 32 + (reg & 3) + ((reg >> 2) << 3) + (hig << 2);
                f32x2 bw = *(const f32x2*)(&bw_lds[2 * j]);
                arg0[q] = fmaf(2.885390082f, acc0[reg], bw.x);
                arg1[q] = fmaf(2.885390082f, acc1[reg], bw.x);
                w4[q]   = bw.y;
            }
            tanh4(arg0, w4, s0);
            tanh4(arg1, w4, s1);
        }
        s0 += __shfl_xor(s0, 32, 64);
        s1 += __shfl_xor(s1, 32, 64);
        if (hig == 0) {
            u_part[wv][l31]      = s0;
            u_part[wv][32 + l31] = s1;
        }
        __syncthreads();

        // ---- phase 2: one wave per piece (piece <= 64 rows) ----
        for (int i = wv; ; i += 4) {
            int st, en;
            if (i < 63) {
                st = __shfl(sv, i, 64);
                en = __shfl(sv, i + 1, 64);
            } else {
                int s0i = sseg0 + i;
                st = seg_start[(s0i     <= S) ? s0i     : S];
                en = seg_start[(s0i + 1 <= S) ? s0i + 1 : S];
            }
            if (st >= rbase + limit) break;    // starts monotone -> done
            if (en <= st) continue;            // empty segment
            int a  = st - rbase; if (a < 0) a = 0;
            int bb = en - rbase; if (bb > limit) bb = limit;
            if (a >= bb) continue;

            float uv = -INFINITY;
            if (a + lane < bb)
                uv = u_part[0][a + lane] + u_part[1][a + lane]
                   + u_part[2][a + lane] + u_part[3][a + lane];
            float m = uv;
            #pragma unroll
            for (int o = 32; o > 0; o >>= 1) m = fmaxf(m, __shfl_xor(m, o, 64));
            float e0 = (a + lane < bb) ? exp2_fast((uv - m) * 1.442695041f) : 0.0f;
            float d = e0;
            #pragma unroll
            for (int o = 32; o > 0; o >>= 1) d += __shfl_xor(d, o, 64);
            if (a + lane < bb) w_lds[a + lane] = e0;

            // p[c] = sum_r e_r * x[r][c]; lane owns cols {2*lane, 2*lane+1}
            f32x2 p = {0.0f, 0.0f};
            int rr = a;
            for (; rr + 4 <= bb; rr += 4) {
                #pragma unroll
                for (int q = 0; q < 4; ++q) {
                    int rc = rr + q;
                    float wq = w_lds[rc];
                    unsigned pr = *(const unsigned*)(&X_lds[rc * XP + 2 * lane]);
                    float x0 = __builtin_bit_cast(float, pr << 16);
                    float x1 = __builtin_bit_cast(float, pr & 0xFFFF0000u);
                    p.x = fmaf(wq, x0, p.x);
                    p.y = fmaf(wq, x1, p.y);
                }
            }
            for (; rr < bb; ++rr) {
                float wq = w_lds[rr];
                unsigned pr = *(const unsigned*)(&X_lds[rr * XP + 2 * lane]);
                float x0 = __builtin_bit_cast(float, pr << 16);
                float x1 = __builtin_bit_cast(float, pr & 0xFFFF0000u);
                p.x = fmaf(wq, x0, p.x);
                p.y = fmaf(wq, x1, p.y);
            }

            int sseg = sseg0 + i;
            int slot = (T - (st >> 6)) & (MAXK - 1);
            float* dst = pieces + ((size_t)sseg * MAXK + slot) * PIECE_F;
            if (lane == 0) { dst[0] = m; dst[1] = d; }
            *(f32x2*)(dst + 4 + 2 * lane) = p;
        }
        __syncthreads();   // X_lds/w_lds reads done before next tile's stage
    }
}

// ---------------------------------------------------------------------------
// Fixup: merge pieces per segment -> z[s][:].
// ---------------------------------------------------------------------------
__global__ __launch_bounds__(64) void fixup_kernel(
    const float* __restrict__ pieces, const int* __restrict__ seg_start,
    float* __restrict__ z)
{
    const int s = blockIdx.x;
    const int lane = threadIdx.x;
    const int start = seg_start[s];
    const int end   = seg_start[s + 1];

    if (start >= end) {
        f32x2 zo = {0.0f, 0.0f};
        *(f32x2*)(z + (size_t)s * HID + lane * 2) = zo;
        return;
    }
    int K = ((end - 1) >> 6) - (start >> 6) + 1;
    if (K > MAXK) K = MAXK;

    const float* base0 = pieces + (size_t)s * MAXK * PIECE_F;
    float M = -INFINITY;
    for (int k = 0; k < K; ++k) M = fmaxf(M, base0[k * PIECE_F]);

    float D = 0.0f;
    f32x2 zz = {0.0f, 0.0f};
    for (int k = 0; k < K; ++k) {
        const float* b = base0 + k * PIECE_F;
        float sc = __expf(b[0] - M);
        D = fmaf(b[1], sc, D);
        f32x2 pv = *(const f32x2*)(b + 4 + lane * 2);
        zz.x = fmaf(sc, pv.x, zz.x);
        zz.y = fmaf(sc, pv.y, zz.y);
    }
    float inv = 1.0f / D;
    f32x2 zo = {zz.x * inv, zz.y * inv};
    *(f32x2*)(z + (size_t)s * HID + lane * 2) = zo;
}

// ---------------------------------------------------------------------------
extern "C" void kernel_launch(void* const* d_in, const int* in_sizes, int n_in,
                              void* d_out, int out_size, void* d_ws, size_t ws_size,
                              hipStream_t stream)
{
    const float* X   = (const float*)d_in[0];
    const int*   ow  = (const int*)  d_in[1];
    const float* W   = (const float*)d_in[2];
    const float* bp  = (const float*)d_in[3];
    const float* wsc = (const float*)d_in[4];

    const int N  = in_sizes[0] / HID;
    const int S  = out_size / HID;
    const int NT = (N + TM - 1) / TM;

    char* ws = (char*)d_ws;
    size_t off_seg = 0;
    size_t off_fs  = (((size_t)(S + 1) * 4) + 255) & ~(size_t)255;
    size_t off_w   = (off_fs + (size_t)NT * 4 + 255) & ~(size_t)255;
    size_t off_pc  = (off_w + (size_t)HID * HID * 2 + 255) & ~(size_t)255;

    int*   seg    = (int*)  (ws + off_seg);
    int*   fsg    = (int*)  (ws + off_fs);
    short* whi    = (short*)(ws + off_w);
    float* pieces = (float*)(ws + off_pc);
    float* z      = (float*)d_out;

    const int blocksB = ((N + 1) + 255) / 256;
    seg_start_kernel<<<blocksB, 256, 0, stream>>>(ow, seg, fsg, N, S);

    prep_w_frag<<<8, 256, 0, stream>>>(W, whi);

    const int grid = (NT + TPB - 1) / TPB;
    fused_kernel<<<grid, 256, 0, stream>>>(X, whi, bp, wsc, seg, fsg,
                                           pieces, N, S, NT);

    fixup_kernel<<<S, 64, 0, stream>>>(pieces, seg, z);
}

// Round 18
// 123.855 us; speedup vs baseline: 1.1465x; 1.1465x over previous
//
#include <hip/hip_runtime.h>
#include <hip/hip_bf16.h>
#include <cmath>

#define HID 128
#define TM 64           // tile rows per block
#define MAXK 8          // max tiles a segment can span (seg len <= ~512)
#define PIECE_F 132     // floats per piece: [m, d, pad, pad, p[128]]
#define XP 132          // shorts per LDS X row: 264B pitch -> <=2-way banks

typedef __attribute__((ext_vector_type(8))) short bf16x8;
typedef __attribute__((ext_vector_type(16))) float f32x16;
typedef __attribute__((ext_vector_type(4))) float f32x4;
typedef __attribute__((ext_vector_type(2))) float f32x2;

__device__ __forceinline__ float exp2_fast(float x) {
    float r;
    asm("v_exp_f32 %0, %1" : "=v"(r) : "v"(x));
    return r;
}

// tanh(x) = 1 - 2/(2^(2*log2e*x) + 1)
__device__ __forceinline__ float fast_tanh(float x) {
    float e = exp2_fast(x * 2.885390082f);
    return 1.0f - 2.0f * __builtin_amdgcn_rcpf(e + 1.0f);
}

// Pack 8 floats -> 8 bf16 RNE via hardware cvt (pairs into v_cvt_pk_bf16_f32).
__device__ __forceinline__ bf16x8 pack8(const float* f) {
    union { short h8[8]; bf16x8 v; } u;
    #pragma unroll
    for (int q = 0; q < 8; ++q)
        u.h8[q] = (short)__bfloat16_as_ushort(__float2bfloat16(f[q]));
    return u.v;
}

// ---------------------------------------------------------------------------
// Merged prep: blocks 0..7 convert W -> bf16 fragments (32x32x16 per-wave
// register order: id=(wv*8+kc)*64+lane holds W[wv*32+(lane&31)]
// [kc*16+(lane>>5)*8+q]); blocks 8.. compute segment starts from sorted
// owners (int32/int64) + first-segment per TM-tile.
// ---------------------------------------------------------------------------
__global__ __launch_bounds__(256) void prep_kernel(
    const int* __restrict__ ow, int* __restrict__ seg_start,
    int* __restrict__ fseg, const float* __restrict__ W,
    short* __restrict__ whi, int N, int S)
{
    const int b = blockIdx.x;
    if (b < 8) {
        int id = b * 256 + threadIdx.x;             // 0..2047
        int l  = id & 63;
        int kc = (id >> 6) & 7;
        int wv = id >> 9;                           // 0..3
        int j  = wv * 32 + (l & 31);
        int k0 = kc * 16 + ((l >> 5) << 3);
        const float* src = W + j * HID + k0;
        float a8[8];
        #pragma unroll
        for (int q = 0; q < 8; ++q) a8[q] = src[q];
        *(bf16x8*)(whi + (size_t)id * 8) = pack8(a8);
        return;
    }
    const int is64 = (ow[(size_t)N - 1] == 0) ? 1 : 0;
    long i = (long)(b - 8) * 256 + threadIdx.x;
    if (i > N) return;
    int a = (i == 0) ? -1 : ow[is64 ? (size_t)(2 * (i - 1)) : (size_t)(i - 1)];
    int bb = (i == N) ? S : ow[is64 ? (size_t)(2 * i) : (size_t)i];
    for (int s = a + 1; s <= bb; ++s) seg_start[s] = (int)i;
    if (i < N && (i & (TM - 1)) == 0) fseg[i >> 6] = bb;  // owner of row i
}

// ---------------------------------------------------------------------------
// Fused (exact round-12 champion, 125.9us): 64-row tile, j-split waves with
// W slice in 32 VGPRs loaded once; X bf16 in LDS pitch XP; one wave/piece.
// ---------------------------------------------------------------------------
__global__ __launch_bounds__(256, 4) void fused_kernel(
    const float* __restrict__ X, const short* __restrict__ whi_g,
    const float* __restrict__ bproj, const float* __restrict__ wscore,
    const int* __restrict__ seg_start, const int* __restrict__ fseg,
    float* __restrict__ pieces, int N, int S)
{
    __shared__ __align__(16) short X_lds[TM * XP];   // ~16.9 KB
    __shared__ float u_part[4][TM];
    __shared__ float w_lds[TM];
    __shared__ float bw_lds[2 * HID];                // packed {b[j], w[j]}

    const int tid  = threadIdx.x;
    const int bIdx = blockIdx.x;
    const int rbase = bIdx * TM;
    const int limit = (N - rbase < TM) ? (N - rbase) : TM;

    const int lane = tid & 63;
    const int wv   = tid >> 6;
    const int l31  = lane & 31;
    const int hig  = lane >> 5;

    // --- W slice for this wave: 8 frags = 32 VGPRs, loaded once ---
    bf16x8 wf[8];
    #pragma unroll
    for (int kc = 0; kc < 8; ++kc)
        wf[kc] = *(const bf16x8*)(whi_g + (size_t)((wv * 8 + kc) * 64 + lane) * 8);

    const int sseg0 = fseg[bIdx];
    int svl = sseg0 + lane;
    int sv  = seg_start[(svl <= S) ? svl : S];

    // --- stage X: read 32B f32, cvt bf16, write 16B chunk (pitch XP) ---
    #pragma unroll
    for (int it = 0; it < 4; ++it) {
        int id = it * 256 + tid;          // 0..1023
        int r  = id >> 4;                 // 0..63
        int c  = id & 15;                 // 8-elem chunk
        int grow = rbase + r;
        if (grow >= N) grow = N - 1;
        float a8[8];
        *(f32x4*)(a8)     = *(const f32x4*)(X + (size_t)grow * HID + c * 8);
        *(f32x4*)(a8 + 4) = *(const f32x4*)(X + (size_t)grow * HID + c * 8 + 4);
        *(bf16x8*)(&X_lds[r * XP + c * 8]) = pack8(a8);
    }
    if (tid < HID) {
        bw_lds[2 * tid]     = bproj[tid];
        bw_lds[2 * tid + 1] = wscore[tid];
    }
    __syncthreads();

    // ---- MFMA 32x32x16: acc0 covers i=l31, acc1 covers i=32+l31 ----
    f32x16 acc0, acc1;
    #pragma unroll
    for (int g = 0; g < 16; ++g) { acc0[g] = 0.0f; acc1[g] = 0.0f; }

    #pragma unroll
    for (int kc = 0; kc < 8; ++kc) {
        int c = kc * 2 + hig;             // chunk holding this lane's k-octet
        bf16x8 x0 = *(const bf16x8*)(&X_lds[l31 * XP + c * 8]);
        bf16x8 x1 = *(const bf16x8*)(&X_lds[(32 + l31) * XP + c * 8]);
        acc0 = __builtin_amdgcn_mfma_f32_32x32x16_bf16(wf[kc], x0, acc0, 0, 0, 0);
        acc1 = __builtin_amdgcn_mfma_f32_32x32x16_bf16(wf[kc], x1, acc1, 0, 0, 0);
    }

    // ---- epilogue: partial u over this wave's 32 j's ----
    // D layout (32x32): col i = lane&31; row j = (reg&3)+8*(reg>>2)+4*hig
    float s0 = 0.0f, s1 = 0.0f;
    #pragma unroll
    for (int reg = 0; reg < 16; ++reg) {
        int j = wv * 32 + (reg & 3) + ((reg >> 2) << 3) + (hig << 2);
        f32x2 bw = *(const f32x2*)(&bw_lds[2 * j]);
        s0 = fmaf(fast_tanh(acc0[reg] + bw.x), bw.y, s0);
        s1 = fmaf(fast_tanh(acc1[reg] + bw.x), bw.y, s1);
    }
    s0 += __shfl_xor(s0, 32, 64);
    s1 += __shfl_xor(s1, 32, 64);
    if (hig == 0) {
        u_part[wv][l31]      = s0;
        u_part[wv][32 + l31] = s1;
    }
    __syncthreads();

    // ---- phase 2: one wave per piece (piece <= 64 rows) ----
    for (int i = wv; ; i += 4) {
        int st, en;
        if (i < 63) {
            st = __shfl(sv, i, 64);
            en = __shfl(sv, i + 1, 64);
        } else {
            int s0i = sseg0 + i;
            st = seg_start[(s0i     <= S) ? s0i     : S];
            en = seg_start[(s0i + 1 <= S) ? s0i + 1 : S];
        }
        if (st >= rbase + limit) break;    // starts monotone -> done
        if (en <= st) continue;            // empty segment
        int a  = st - rbase; if (a < 0) a = 0;
        int bb = en - rbase; if (bb > limit) bb = limit;
        if (a >= bb) continue;

        float uv = -INFINITY;
        if (a + lane < bb)
            uv = u_part[0][a + lane] + u_part[1][a + lane]
               + u_part[2][a + lane] + u_part[3][a + lane];
        float m = uv;
        #pragma unroll
        for (int o = 32; o > 0; o >>= 1) m = fmaxf(m, __shfl_xor(m, o, 64));
        float e0 = (a + lane < bb) ? exp2_fast((uv - m) * 1.442695041f) : 0.0f;
        float d = e0;
        #pragma unroll
        for (int o = 32; o > 0; o >>= 1) d += __shfl_xor(d, o, 64);
        if (a + lane < bb) w_lds[a + lane] = e0;

        // p[c] = sum_r e_r * x[r][c]; lane owns cols {2*lane, 2*lane+1}
        f32x2 p = {0.0f, 0.0f};
        int rr = a;
        for (; rr + 4 <= bb; rr += 4) {
            #pragma unroll
            for (int q = 0; q < 4; ++q) {
                int rc = rr + q;
                float wq = w_lds[rc];
                unsigned pr = *(const unsigned*)(&X_lds[rc * XP + 2 * lane]);
                float x0 = __builtin_bit_cast(float, pr << 16);
                float x1 = __builtin_bit_cast(float, pr & 0xFFFF0000u);
                p.x = fmaf(wq, x0, p.x);
                p.y = fmaf(wq, x1, p.y);
            }
        }
        for (; rr < bb; ++rr) {
            float wq = w_lds[rr];
            unsigned pr = *(const unsigned*)(&X_lds[rr * XP + 2 * lane]);
            float x0 = __builtin_bit_cast(float, pr << 16);
            float x1 = __builtin_bit_cast(float, pr & 0xFFFF0000u);
            p.x = fmaf(wq, x0, p.x);
            p.y = fmaf(wq, x1, p.y);
        }

        int sseg = sseg0 + i;
        int slot = (bIdx - (st >> 6)) & (MAXK - 1);
        float* dst = pieces + ((size_t)sseg * MAXK + slot) * PIECE_F;
        if (lane == 0) { dst[0] = m; dst[1] = d; }
        *(f32x2*)(dst + 4 + 2 * lane) = p;
    }
}

// ---------------------------------------------------------------------------
// Fixup: merge pieces per segment -> z[s][:]. 4 segments per 256-thr block
// (one 64-lane wave each) to cut dispatch count 4x.
// ---------------------------------------------------------------------------
__global__ __launch_bounds__(256) void fixup_kernel(
    const float* __restrict__ pieces, const int* __restrict__ seg_start,
    float* __restrict__ z, int S)
{
    const int s = blockIdx.x * 4 + (threadIdx.x >> 6);
    if (s >= S) return;
    const int lane = threadIdx.x & 63;
    const int start = seg_start[s];
    const int end   = seg_start[s + 1];

    if (start >= end) {
        f32x2 zo = {0.0f, 0.0f};
        *(f32x2*)(z + (size_t)s * HID + lane * 2) = zo;
        return;
    }
    int K = ((end - 1) >> 6) - (start >> 6) + 1;
    if (K > MAXK) K = MAXK;

    const float* base0 = pieces + (size_t)s * MAXK * PIECE_F;
    float M = -INFINITY;
    for (int k = 0; k < K; ++k) M = fmaxf(M, base0[k * PIECE_F]);

    float D = 0.0f;
    f32x2 zz = {0.0f, 0.0f};
    for (int k = 0; k < K; ++k) {
        const float* b = base0 + k * PIECE_F;
        float sc = __expf(b[0] - M);
        D = fmaf(b[1], sc, D);
        f32x2 pv = *(const f32x2*)(b + 4 + lane * 2);
        zz.x = fmaf(sc, pv.x, zz.x);
        zz.y = fmaf(sc, pv.y, zz.y);
    }
    float inv = 1.0f / D;
    f32x2 zo = {zz.x * inv, zz.y * inv};
    *(f32x2*)(z + (size_t)s * HID + lane * 2) = zo;
}

// ---------------------------------------------------------------------------
extern "C" void kernel_launch(void* const* d_in, const int* in_sizes, int n_in,
                              void* d_out, int out_size, void* d_ws, size_t ws_size,
                              hipStream_t stream)
{
    const float* X   = (const float*)d_in[0];
    const int*   ow  = (const int*)  d_in[1];
    const float* W   = (const float*)d_in[2];
    const float* bp  = (const float*)d_in[3];
    const float* wsc = (const float*)d_in[4];

    const int N  = in_sizes[0] / HID;
    const int S  = out_size / HID;
    const int NT = (N + TM - 1) / TM;

    char* ws = (char*)d_ws;
    size_t off_seg = 0;
    size_t off_fs  = (((size_t)(S + 1) * 4) + 255) & ~(size_t)255;
    size_t off_w   = (off_fs + (size_t)NT * 4 + 255) & ~(size_t)255;
    size_t off_pc  = (off_w + (size_t)HID * HID * 2 + 255) & ~(size_t)255;

    int*   seg    = (int*)  (ws + off_seg);
    int*   fsg    = (int*)  (ws + off_fs);
    short* whi    = (short*)(ws + off_w);
    float* pieces = (float*)(ws + off_pc);
    float* z      = (float*)d_out;

    const int blocksSeg = ((N + 1) + 255) / 256;
    prep_kernel<<<blocksSeg + 8, 256, 0, stream>>>(ow, seg, fsg, W, whi, N, S);

    fused_kernel<<<NT, 256, 0, stream>>>(X, whi, bp, wsc, seg, fsg,
                                         pieces, N, S);

    fixup_kernel<<<(S + 3) / 4, 256, 0, stream>>>(pieces, seg, z, S);
}